// Round 6
// baseline (398.478 us; speedup 1.0000x reference)
//
#include <hip/hip_runtime.h>

#define D_   1024
#define H_   16
#define DHd  64
#define BLK  256
#define B_   4
#define S_   4096
#define NB_  16
#define M_   16384
#define N1_  3072
#define KT_  16          // K tiles of 64

typedef __attribute__((ext_vector_type(8))) short short8;
typedef __attribute__((ext_vector_type(4))) float f32x4;
typedef unsigned short u16;
typedef __attribute__((ext_vector_type(4))) unsigned short u16x4;

__device__ inline u16 f2bf(float f) {
  unsigned int u = __float_as_uint(f);
  unsigned int r = (u + 0x7fffu + ((u >> 16) & 1u)) >> 16;
  return (u16)r;
}

__device__ inline void async_ld16(const void* g, void* l) {
  __builtin_amdgcn_global_load_lds(
      (const __attribute__((address_space(1))) unsigned int*)g,
      (__attribute__((address_space(3))) unsigned int*)l, 16, 0, 0);
}

// ---------------- prep: x[perm] -> bf16, permuted order ----------------
__global__ __launch_bounds__(256)
void permute_cast_kernel(const float* __restrict__ x, const int* __restrict__ perm,
                         u16* __restrict__ xp) {
  int bid = blockIdx.x;
  int b = bid >> 12;
  int i = bid & 4095;
  int prow = perm[b * S_ + i];
  const float4* src = reinterpret_cast<const float4*>(x + (size_t)(b * S_ + prow) * D_);
  float4 v = src[threadIdx.x];
  u16x4 o;
  o.x = f2bf(v.x); o.y = f2bf(v.y); o.z = f2bf(v.z); o.w = f2bf(v.w);
  reinterpret_cast<u16x4*>(xp + (size_t)bid * D_)[threadIdx.x] = o;
}

// ---------------- weight transpose + cast: src[R][C] f32 -> dst[C][R] bf16 ----------------
__global__ __launch_bounds__(256)
void transpose_cast_kernel(const float* __restrict__ src, u16* __restrict__ dst,
                           int R, int C) {
  __shared__ float tile[32][33];
  int tx = threadIdx.x, ty = threadIdx.y;     // block (32,8)
  int c0 = blockIdx.x * 32, r0 = blockIdx.y * 32;
  #pragma unroll
  for (int i = ty; i < 32; i += 8)
    tile[i][tx] = src[(size_t)(r0 + i) * C + c0 + tx];
  __syncthreads();
  #pragma unroll
  for (int i = ty; i < 32; i += 8)
    dst[(size_t)(c0 + i) * R + r0 + tx] = f2bf(tile[tx][i]);
}

// ---------------- 256x256-tile bf16 GEMM, 2-phase single-barrier pipeline ----------------
// A: [M][1024] bf16 (permuted-order rows).  BT: [N][1024] bf16 (k-contiguous).
// 8 waves (2M x 4N), per-wave output 128x64.  BK=64, 2 LDS buffers of 64 KB.
// Per K-tile: STAGE(next buf) issued FIRST, then ds_read+64 MFMA on current,
// then ONE vmcnt(0)+barrier (drain after compute covers the load latency).
// Slot swizzle (128B rows, 8x16B slots): phys = logical ^ (row&7), applied on
// BOTH the pre-swizzled global source and the ds_read address (rule 21).
template<int MODE>
__global__ __launch_bounds__(512)
void gemm_kernel(const u16* __restrict__ A, const u16* __restrict__ BT,
                 const float* __restrict__ bias, const int* __restrict__ perm,
                 u16* __restrict__ q_ws, u16* __restrict__ k_ws, u16* __restrict__ vT_ws,
                 float* __restrict__ out_k, float* __restrict__ out_v,
                 float* __restrict__ out_o) {
  constexpr int NCOL = (MODE == 0) ? N1_ : D_;
  constexpr int NPAN = NCOL / 256;
  constexpr int NWG  = (M_ / 256) * NPAN;
  constexpr int CPX  = NWG / 8;               // NWG % 8 == 0 for both modes

  __shared__ u16 LDS[2 * 32768];              // 128 KiB: 2 bufs x (A 32KB + B 32KB)
  __shared__ int perm_l[256];

  const int tid  = threadIdx.x;
  const int lane = tid & 63;
  const int w    = tid >> 6;
  const int wr   = w >> 2, wc = w & 3;        // 2 x 4 wave grid
  const int l4   = lane >> 4, l15 = lane & 15;

  // XCD-aware bijective swizzle, then n-major panel mapping (A-panel L2 reuse)
  const int orig = blockIdx.x;
  const int lid  = (orig & 7) * CPX + (orig >> 3);
  const int i0   = (lid / NPAN) * 256;
  const int n0   = (lid % NPAN) * 256;
  const int bidx = i0 >> 12;                  // batch (256-tiles never straddle S=4096)

  if (tid < 256) perm_l[tid] = perm[bidx * S_ + (i0 & 4095) + tid];

  // --- staging: round j covers rows j*64..j*64+63; wave w rows w*8..w*8+7.
  //     lane -> (row = w*8 + (lane>>3), phys 16B slot = lane&7); global source
  //     slot pre-swizzled: logical = (lane&7) ^ (lane>>3) = phys ^ (row&7). ---
  const int sl8 = (((lane & 7) ^ (lane >> 3)) << 3);        // element offset
  const u16* pA = A  + (size_t)(i0 + w * 8 + (lane >> 3)) * 1024 + sl8;
  const u16* pB = BT + (size_t)(n0 + w * 8 + (lane >> 3)) * 1024 + sl8;

  // --- reader byte offsets: row*128 + ((kk*4+l4)^(row&7))*16, row&7 == l15&7 ---
  const int pk0 = ((l4)     ^ (l15 & 7)) * 16;
  const int pk1 = ((4 + l4) ^ (l15 & 7)) * 16;
  const int abase = (wr * 128 + l15) * 128;                 // + m*2048 + pk
  const int bbase = 32768 + (wc * 64 + l15) * 128;          // + n*2048 + pk

  f32x4 acc[8][4] = {};

  #define STAGE(kt, b) do {                                    \
    const size_t ko_ = (size_t)(kt) * 64;                      \
    u16* d_ = &LDS[(b) * 32768 + w * 512];                     \
    async_ld16(pA + ko_,              d_);                     \
    async_ld16(pA + ko_ +  64 * 1024, d_ + 4096);              \
    async_ld16(pA + ko_ + 128 * 1024, d_ + 8192);              \
    async_ld16(pA + ko_ + 192 * 1024, d_ + 12288);             \
    async_ld16(pB + ko_,              d_ + 16384);             \
    async_ld16(pB + ko_ +  64 * 1024, d_ + 20480);             \
    async_ld16(pB + ko_ + 128 * 1024, d_ + 24576);             \
    async_ld16(pB + ko_ + 192 * 1024, d_ + 28672);             \
  } while (0)

  #define COMPUTE(b) do {                                                         \
    const char* lb_ = (const char*)LDS + (b) * 65536;                             \
    _Pragma("unroll")                                                             \
    for (int kk = 0; kk < 2; ++kk) {                                              \
      const int pk_ = kk ? pk1 : pk0;                                             \
      short8 af_[8], bf_[4];                                                      \
      _Pragma("unroll")                                                           \
      for (int m = 0; m < 8; ++m)                                                 \
        af_[m] = *reinterpret_cast<const short8*>(lb_ + abase + m * 2048 + pk_);  \
      _Pragma("unroll")                                                           \
      for (int n = 0; n < 4; ++n)                                                 \
        bf_[n] = *reinterpret_cast<const short8*>(lb_ + bbase + n * 2048 + pk_);  \
      asm volatile("s_waitcnt lgkmcnt(0)" ::: "memory");                          \
      __builtin_amdgcn_sched_barrier(0);                                          \
      __builtin_amdgcn_s_setprio(1);                                              \
      _Pragma("unroll")                                                           \
      for (int m = 0; m < 8; ++m)                                                 \
        _Pragma("unroll")                                                         \
        for (int n = 0; n < 4; ++n)                                               \
          acc[m][n] = __builtin_amdgcn_mfma_f32_16x16x32_bf16(af_[m], bf_[n], acc[m][n], 0, 0, 0); \
      __builtin_amdgcn_s_setprio(0);                                              \
    }                                                                             \
  } while (0)

  STAGE(0, 0);
  asm volatile("s_waitcnt vmcnt(0)" ::: "memory");
  __builtin_amdgcn_s_barrier();
  #pragma unroll 2
  for (int kt = 0; kt < KT_ - 1; ++kt) {
    STAGE(kt + 1, (kt + 1) & 1);   // issue next tile's loads FIRST
    COMPUTE(kt & 1);               // ~2500 SIMD-cyc of MFMA covers the latency
    asm volatile("s_waitcnt vmcnt(0)" ::: "memory");
    __builtin_amdgcn_s_barrier();  // next buffer staged + this buffer's reads retired
  }
  COMPUTE((KT_ - 1) & 1);
  #undef STAGE
  #undef COMPUTE

  // ---- epilogue ----  C layout: row = (lane>>4)*4 + r (+16*m), col = lane&15 (+16*n)
  if (MODE == 0) {
    #pragma unroll
    for (int n = 0; n < 4; ++n) {
      int col = n0 + wc * 64 + n * 16 + l15;
      float bias_v = bias[col];
      int h  = col / 192;
      int rem = col - h * 192;
      int cc = rem >> 6;
      int dd = rem & 63;
      int qcol = (h << 6) + dd;
      #pragma unroll
      for (int m = 0; m < 8; ++m) {
        int rbase = i0 + wr * 128 + m * 16 + l4 * 4;
        if (cc == 0) {
          #pragma unroll
          for (int r = 0; r < 4; ++r)
            q_ws[(size_t)(rbase + r) * D_ + qcol] = f2bf(acc[m][n][r] + bias_v);
        } else if (cc == 1) {
          #pragma unroll
          for (int r = 0; r < 4; ++r) {
            float val = acc[m][n][r] + bias_v;
            int rr = rbase + r;
            k_ws[(size_t)rr * D_ + qcol] = f2bf(val);
            int prow = perm_l[rr - i0];
            out_k[(size_t)(bidx * S_ + prow) * D_ + qcol] = val;
          }
        } else {
          u16x4 pk;
          #pragma unroll
          for (int r = 0; r < 4; ++r) {
            float val = acc[m][n][r] + bias_v;
            int rr = rbase + r;
            int prow = perm_l[rr - i0];
            out_v[(size_t)(bidx * S_ + prow) * D_ + qcol] = val;
            pk[r] = f2bf(val);
          }
          int i_loc = rbase & 4095;
          int nblk = i_loc >> 8;
          int t    = i_loc & 255;
          *reinterpret_cast<u16x4*>(
              &vT_ws[((((size_t)bidx * NB_ + nblk) * H_ + h) * DHd + dd) * BLK + t]) = pk;
        }
      }
    }
  } else {
    #pragma unroll
    for (int n = 0; n < 4; ++n) {
      int col = n0 + wc * 64 + n * 16 + l15;
      float bias_v = bias[col];
      #pragma unroll
      for (int m = 0; m < 8; ++m) {
        int rbase = i0 + wr * 128 + m * 16 + l4 * 4;
        #pragma unroll
        for (int r = 0; r < 4; ++r) {
          int rr = rbase + r;
          int prow = perm_l[rr - i0];
          out_o[(size_t)(bidx * S_ + prow) * D_ + col] = acc[m][n][r] + bias_v;
        }
      }
    }
  }
}

// ---------------- block attention: 1 block per (b, nblk, h), 4 waves x 64 rows ----------------
__global__ __launch_bounds__(256)
void attn_kernel(const u16* __restrict__ q_ws, const u16* __restrict__ k_ws,
                 const u16* __restrict__ vT_ws, u16* __restrict__ o_ws) {
  __shared__ u16 P_lds[4 * 64 * 64];   // per-wave 64x64 bf16 P tile

  int bid  = blockIdx.x;
  int h    = bid & 15;
  int nblk = (bid >> 4) & 15;
  int b    = bid >> 8;
  int row0 = b * S_ + nblk * BLK;
  int lane = threadIdx.x & 63;
  int w    = threadIdx.x >> 6;
  int l4 = lane >> 4, l15 = lane & 15;

  const u16* qb  = q_ws + (size_t)row0 * D_ + h * 64;
  const u16* kb  = k_ws + (size_t)row0 * D_ + h * 64;
  const u16* vTb = vT_ws + ((size_t)(b * NB_ + nblk) * H_ + h) * (size_t)(DHd * BLK);

  short8 qf[4][2];
  #pragma unroll
  for (int mt = 0; mt < 4; ++mt)
    #pragma unroll
    for (int kk = 0; kk < 2; ++kk)
      qf[mt][kk] = *reinterpret_cast<const short8*>(
          qb + (size_t)(w * 64 + mt * 16 + l15) * D_ + kk * 32 + l4 * 8);

  f32x4 Oacc[4][4] = {};
  float mS[4][4], lS[4][4];
  #pragma unroll
  for (int mt = 0; mt < 4; ++mt)
    #pragma unroll
    for (int r = 0; r < 4; ++r) { mS[mt][r] = -1e30f; lS[mt][r] = 0.f; }

  for (int ct = 0; ct < 4; ++ct) {
    f32x4 Sc[4][4] = {};
    #pragma unroll
    for (int kk = 0; kk < 2; ++kk) {
      #pragma unroll
      for (int nt = 0; nt < 4; ++nt) {
        short8 kf = *reinterpret_cast<const short8*>(
            kb + (size_t)(ct * 64 + nt * 16 + l15) * D_ + kk * 32 + l4 * 8);
        #pragma unroll
        for (int mt = 0; mt < 4; ++mt)
          Sc[mt][nt] = __builtin_amdgcn_mfma_f32_16x16x32_bf16(qf[mt][kk], kf, Sc[mt][nt], 0, 0, 0);
      }
    }
    #pragma unroll
    for (int mt = 0; mt < 4; ++mt) {
      #pragma unroll
      for (int r = 0; r < 4; ++r) {
        float v0 = fmaxf(fmaxf(Sc[mt][0][r], Sc[mt][1][r]), fmaxf(Sc[mt][2][r], Sc[mt][3][r]));
        v0 *= 0.125f;
        v0 = fmaxf(v0, __shfl_xor(v0, 1));
        v0 = fmaxf(v0, __shfl_xor(v0, 2));
        v0 = fmaxf(v0, __shfl_xor(v0, 4));
        v0 = fmaxf(v0, __shfl_xor(v0, 8));
        float mn = fmaxf(mS[mt][r], v0);
        float alpha = __expf(mS[mt][r] - mn);
        mS[mt][r] = mn;
        float rs = 0.f;
        #pragma unroll
        for (int nt = 0; nt < 4; ++nt) {
          float p = __expf(Sc[mt][nt][r] * 0.125f - mn);
          Sc[mt][nt][r] = p;
          rs += p;
        }
        rs += __shfl_xor(rs, 1);
        rs += __shfl_xor(rs, 2);
        rs += __shfl_xor(rs, 4);
        rs += __shfl_xor(rs, 8);
        lS[mt][r] = lS[mt][r] * alpha + rs;
        #pragma unroll
        for (int nt = 0; nt < 4; ++nt)
          Oacc[mt][nt][r] *= alpha;
      }
    }
    #pragma unroll
    for (int mt = 0; mt < 4; ++mt)
      #pragma unroll
      for (int nt = 0; nt < 4; ++nt)
        #pragma unroll
        for (int r = 0; r < 4; ++r)
          P_lds[w * 4096 + (mt * 16 + l4 * 4 + r) * 64 + nt * 16 + l15] = f2bf(Sc[mt][nt][r]);
    #pragma unroll
    for (int kk = 0; kk < 2; ++kk) {
      short8 pa[4];
      #pragma unroll
      for (int mt = 0; mt < 4; ++mt)
        pa[mt] = *reinterpret_cast<const short8*>(
            &P_lds[w * 4096 + (mt * 16 + l15) * 64 + kk * 32 + l4 * 8]);
      #pragma unroll
      for (int nt = 0; nt < 4; ++nt) {
        short8 vf = *reinterpret_cast<const short8*>(
            vTb + (size_t)(nt * 16 + l15) * BLK + ct * 64 + kk * 32 + l4 * 8);
        #pragma unroll
        for (int mt = 0; mt < 4; ++mt)
          Oacc[mt][nt] = __builtin_amdgcn_mfma_f32_16x16x32_bf16(pa[mt], vf, Oacc[mt][nt], 0, 0, 0);
      }
    }
  }
  u16* ob = o_ws + (size_t)row0 * D_ + h * 64;
  #pragma unroll
  for (int mt = 0; mt < 4; ++mt)
    #pragma unroll
    for (int r = 0; r < 4; ++r) {
      float inv = 1.f / lS[mt][r];
      int row = w * 64 + mt * 16 + l4 * 4 + r;
      #pragma unroll
      for (int nt = 0; nt < 4; ++nt)
        ob[(size_t)row * D_ + nt * 16 + l15] = f2bf(Oacc[mt][nt][r] * inv);
    }
}

extern "C" void kernel_launch(void* const* d_in, const int* in_sizes, int n_in,
                              void* d_out, int out_size, void* d_ws, size_t ws_size,
                              hipStream_t stream) {
  const float* x     = (const float*)d_in[0];
  const int*   perm  = (const int*)d_in[1];
  const float* W_in  = (const float*)d_in[2];
  const float* b_in  = (const float*)d_in[3];
  const float* W_out = (const float*)d_in[4];
  const float* b_out = (const float*)d_in[5];

  float* out_o = (float*)d_out;
  float* out_k = out_o + (size_t)M_ * D_;
  float* out_v = out_k + (size_t)M_ * D_;

  const size_t nE = (size_t)M_ * D_;
  u16 *xp, *q_ws, *k_ws, *vT, *o_ws, *WinT, *WoutT;
  size_t need_full = (5 * nE + (size_t)N1_ * D_ + (size_t)D_ * D_) * 2;
  if (ws_size >= need_full) {
    u16* w = (u16*)d_ws;
    xp = w; q_ws = xp + nE; k_ws = q_ws + nE; vT = k_ws + nE; o_ws = vT + nE;
    WinT = o_ws + nE; WoutT = WinT + (size_t)N1_ * D_;
  } else {
    // park xp/q_ws in the o-chunk of d_out (GEMM3 fully overwrites it last)
    xp = (u16*)d_out; q_ws = xp + nE;
    u16* w = (u16*)d_ws;
    k_ws = w; vT = k_ws + nE; o_ws = vT + nE;
    WinT = o_ws + nE; WoutT = WinT + (size_t)N1_ * D_;
  }

  permute_cast_kernel<<<M_, 256, 0, stream>>>(x, perm, xp);
  transpose_cast_kernel<<<dim3(N1_ / 32, D_ / 32), dim3(32, 8), 0, stream>>>(W_in, WinT, D_, N1_);
  transpose_cast_kernel<<<dim3(D_ / 32, D_ / 32), dim3(32, 8), 0, stream>>>(W_out, WoutT, D_, D_);
  gemm_kernel<0><<<(M_ / 256) * (N1_ / 256), 512, 0, stream>>>(
      xp, WinT, b_in, perm, q_ws, k_ws, vT, out_k, out_v, nullptr);
  attn_kernel<<<B_ * NB_ * H_, 256, 0, stream>>>(q_ws, k_ws, vT, o_ws);
  gemm_kernel<1><<<(M_ / 256) * (D_ / 256), 512, 0, stream>>>(
      o_ws, WoutT, b_out, perm, nullptr, nullptr, nullptr, nullptr, nullptr, out_o);
}